// Round 3
// baseline (278.103 us; speedup 1.0000x reference)
//
#include <hip/hip_runtime.h>

typedef _Float16 half8 __attribute__((ext_vector_type(8)));
typedef _Float16 half4_t __attribute__((ext_vector_type(4)));
typedef float floatx4 __attribute__((ext_vector_type(4)));

static constexpr int NB  = 32;    // batches
static constexpr int NP  = 4096;  // points per batch
static constexpr int DD  = 128;   // dim
static constexpr int KC  = 64;    // clusters
static constexpr int TN  = 64;    // points per tile
static constexpr int TPB = 2;     // tiles per block
static constexpr int BPB = NP / (TPB * TN);  // 32 blocks per batch
static constexpr int SCP = 136;   // sclo pitch (halfwords)
static constexpr int STP = 72;    // sxt / sat pitch (halfwords)

#define ALPHA_  100.0f
#define LOG2E_  1.44269504088896f

// Fused: distances -> softmax -> partial vlad (atomics) -> last block per
// batch finalizes (subtract colsum*c, L2-normalize, write out).
__global__ __launch_bounds__(256, 3)
void vlad_fused(const float* __restrict__ xg, const float* __restrict__ cg,
                float* __restrict__ vlad, float* __restrict__ colsum,
                int* __restrict__ cnt, float* __restrict__ out)
{
    __shared__ __align__(16) _Float16 sxt[DD][STP];   // x tile fp16^T [d][n^swz]
    __shared__ __align__(16) _Float16 sat[KC][STP];   // softmax a^T [k][n^swz]
    __shared__ __align__(16) _Float16 sclo[KC][SCP];  // centroid lo residual [k][d]
    __shared__ float sc2[KC];
    __shared__ float red[4];
    __shared__ int   isLastS;

    const int tid  = threadIdx.x;
    const int lane = tid & 63;
    const int w    = tid >> 6;
    const int l15  = lane & 15;
    const int quad = lane >> 4;
    const int b    = blockIdx.y;
    const float* xb = xg + (size_t)b * NP * DD;

    // ---- centroid prep: hi-frags in registers, lo tile + c2 in LDS ----
    half8 chi[4][4]; // [mt][ks]: lane holds C[mt*16+l15][ks*32+quad*8 .. +7]
#pragma unroll
    for (int mt = 0; mt < 4; ++mt)
#pragma unroll
        for (int ks = 0; ks < 4; ++ks) {
            const float* p = cg + (mt*16 + l15)*DD + ks*32 + quad*8;
            float4 a  = *(const float4*)p;
            float4 bb = *(const float4*)(p + 4);
            half8 h;
            h[0]=(_Float16)a.x;  h[1]=(_Float16)a.y;  h[2]=(_Float16)a.z;  h[3]=(_Float16)a.w;
            h[4]=(_Float16)bb.x; h[5]=(_Float16)bb.y; h[6]=(_Float16)bb.z; h[7]=(_Float16)bb.w;
            chi[mt][ks] = h;
        }
    {
        int k = tid >> 2, qq = tid & 3;
        const float* rp = cg + k*DD + qq*32;
        float c2p = 0.f;
#pragma unroll
        for (int j = 0; j < 8; ++j) {
            float4 v = *(const float4*)(rp + j*4);
            c2p += v.x*v.x + v.y*v.y + v.z*v.z + v.w*v.w;
            half4_t lo;
            lo[0] = (_Float16)(v.x - (float)(_Float16)v.x);
            lo[1] = (_Float16)(v.y - (float)(_Float16)v.y);
            lo[2] = (_Float16)(v.z - (float)(_Float16)v.z);
            lo[3] = (_Float16)(v.w - (float)(_Float16)v.w);
            *(half4_t*)&sclo[k][(qq*8 + j)*4] = lo;
        }
        c2p += __shfl_xor(c2p, 1);
        c2p += __shfl_xor(c2p, 2);
        if (qq == 0) sc2[k] = c2p;
    }
    __syncthreads();   // sclo / sc2 ready

    floatx4 acc2[8];   // vlad partial: row k = w*16+quad*4+r, col d = nt*16+l15
#pragma unroll
    for (int i = 0; i < 8; ++i) acc2[i] = (floatx4){0.f, 0.f, 0.f, 0.f};
    floatx4 accs = (floatx4){0.f, 0.f, 0.f, 0.f};  // colsum via ones-column MFMA

    half8 onesf;       // B[point][col] = (col==0)
#pragma unroll
    for (int j = 0; j < 8; ++j) onesf[j] = (_Float16)((l15 == 0) ? 1.0f : 0.0f);

    const int nloc = w*16 + l15;
    const int scol = nloc ^ (quad << 4);
    const float* xpt = xb + (size_t)(blockIdx.x*TPB*TN + nloc)*DD + quad*8;

    // ---- prologue: load tile 0 ----
    float4 fa[4], fb[4];
#pragma unroll
    for (int ks = 0; ks < 4; ++ks) {
        fa[ks] = *(const float4*)(xpt + ks*32);
        fb[ks] = *(const float4*)(xpt + ks*32 + 4);
    }

#pragma unroll
    for (int tt = 0; tt < TPB; ++tt) {
        // ---- convert staged fp32 -> fp16 frags; ssq; free fa/fb ----
        half8 xf[4];
        float ssq = 0.f;
#pragma unroll
        for (int ks = 0; ks < 4; ++ks) {
            half8 h;
            h[0]=(_Float16)fa[ks].x; h[1]=(_Float16)fa[ks].y;
            h[2]=(_Float16)fa[ks].z; h[3]=(_Float16)fa[ks].w;
            h[4]=(_Float16)fb[ks].x; h[5]=(_Float16)fb[ks].y;
            h[6]=(_Float16)fb[ks].z; h[7]=(_Float16)fb[ks].w;
            xf[ks] = h;
            ssq += fa[ks].x*fa[ks].x + fa[ks].y*fa[ks].y + fa[ks].z*fa[ks].z + fa[ks].w*fa[ks].w
                 + fb[ks].x*fb[ks].x + fb[ks].y*fb[ks].y + fb[ks].z*fb[ks].z + fb[ks].w*fb[ks].w;
        }

        // ---- prefetch next tile early: latency overlaps GEMM1+softmax+GEMM2 ----
        if (tt + 1 < TPB) {
            const float* xr = xpt + (size_t)(tt + 1) * TN * DD;
#pragma unroll
            for (int ks = 0; ks < 4; ++ks) {
                fa[ks] = *(const float4*)(xr + ks*32);
                fb[ks] = *(const float4*)(xr + ks*32 + 4);
            }
        }

        // ---- write x^T (swizzled; 2-way-max = free) ----
#pragma unroll
        for (int ks = 0; ks < 4; ++ks)
#pragma unroll
            for (int j = 0; j < 8; ++j)
                sxt[ks*32 + quad*8 + j][scol] = xf[ks][j];

        // ---- GEMM1: S^T[cluster][point], c = hi + lo ----
        floatx4 acc1[4];
#pragma unroll
        for (int mt = 0; mt < 4; ++mt) acc1[mt] = (floatx4){0.f, 0.f, 0.f, 0.f};
#pragma unroll
        for (int ks = 0; ks < 4; ++ks) {
#pragma unroll
            for (int mt = 0; mt < 4; ++mt) {
                half8 cl = *(const half8*)&sclo[mt*16 + l15][ks*32 + quad*8];
                acc1[mt] = __builtin_amdgcn_mfma_f32_16x16x32_f16(chi[mt][ks], xf[ks], acc1[mt], 0, 0, 0);
                acc1[mt] = __builtin_amdgcn_mfma_f32_16x16x32_f16(cl,          xf[ks], acc1[mt], 0, 0, 0);
            }
        }
        ssq += __shfl_xor(ssq, 16);
        ssq += __shfl_xor(ssq, 32);

        // ---- softmax over 64 clusters for this lane's point ----
        float dist[4][4];
#pragma unroll
        for (int mt = 0; mt < 4; ++mt) {
            floatx4 c2v = *(const floatx4*)&sc2[mt*16 + quad*4];
#pragma unroll
            for (int r = 0; r < 4; ++r) {
                float d2 = ssq + c2v[r] - 2.f*acc1[mt][r];
                dist[mt][r] = sqrtf(fmaxf(d2, 0.f));
            }
        }
        float dmin = dist[0][0];
#pragma unroll
        for (int mt = 0; mt < 4; ++mt)
#pragma unroll
            for (int r = 0; r < 4; ++r) dmin = fminf(dmin, dist[mt][r]);
        dmin = fminf(dmin, __shfl_xor(dmin, 16));
        dmin = fminf(dmin, __shfl_xor(dmin, 32));
        float pv[4][4];
        float psum = 0.f;
#pragma unroll
        for (int mt = 0; mt < 4; ++mt)
#pragma unroll
            for (int r = 0; r < 4; ++r) {
                float e = exp2f((dmin - dist[mt][r]) * (ALPHA_ * LOG2E_));
                pv[mt][r] = e; psum += e;
            }
        psum += __shfl_xor(psum, 16);
        psum += __shfl_xor(psum, 32);
        float invs = 1.0f / psum;
#pragma unroll
        for (int mt = 0; mt < 4; ++mt)
#pragma unroll
            for (int r = 0; r < 4; ++r)
                sat[mt*16 + quad*4 + r][scol] = (_Float16)(pv[mt][r] * invs);
        __syncthreads();   // sxt + sat visible

        // ---- GEMM2: vlad[k][d] += a^T · x ; colsum via ones column ----
#pragma unroll
        for (int ks2 = 0; ks2 < 2; ++ks2) {
            const int nbase = ks2*32 + quad*8;
            half8 af = *(const half8*)&sat[w*16 + l15][nbase ^ ((l15 >> 2) << 4)];
            accs = __builtin_amdgcn_mfma_f32_16x16x32_f16(af, onesf, accs, 0, 0, 0);
#pragma unroll
            for (int nt = 0; nt < 8; ++nt) {
                const int d = nt*16 + l15;
                half8 bf = *(const half8*)&sxt[d][nbase ^ (((d >> 3) & 3) << 4)];
                acc2[nt] = __builtin_amdgcn_mfma_f32_16x16x32_f16(af, bf, acc2[nt], 0, 0, 0);
            }
        }
        __syncthreads();   // reads done before next tile overwrites
    }

    // ---- epilogue: atomics into global accumulators ----
#pragma unroll
    for (int nt = 0; nt < 8; ++nt)
#pragma unroll
        for (int r = 0; r < 4; ++r) {
            int k = w*16 + quad*4 + r;
            int d = nt*16 + l15;
            atomicAdd(&vlad[((size_t)b*KC + k)*DD + d], acc2[nt][r]);
        }
    if (l15 == 0) {
#pragma unroll
        for (int r = 0; r < 4; ++r)
            atomicAdd(&colsum[b*KC + w*16 + quad*4 + r], accs[r]);
    }

    // ---- last block of this batch finalizes ----
    __threadfence();   // release our atomics before signing off
    if (tid == 0) {
        int old = atomicAdd(&cnt[b], 1);
        isLastS = (old == BPB - 1) ? 1 : 0;
    }
    __syncthreads();
    if (!isLastS) return;
    __threadfence();   // acquire: other blocks' vlad/colsum now visible

    float v[32];
    float ss = 0.f;
#pragma unroll
    for (int i = 0; i < 32; ++i) {
        int idx = i*256 + tid;
        // agent-scope loads: bypass per-XCD L2, read the coherent point
        float vl = __hip_atomic_load(&vlad[(size_t)b*8192 + idx],
                                     __ATOMIC_RELAXED, __HIP_MEMORY_SCOPE_AGENT);
        float cv = __hip_atomic_load(&colsum[b*KC + (idx >> 7)],
                                     __ATOMIC_RELAXED, __HIP_MEMORY_SCOPE_AGENT);
        float val = vl - cv * cg[idx];
        v[i] = val;
        ss += val * val;
    }
#pragma unroll
    for (int m = 1; m < 64; m <<= 1) ss += __shfl_xor(ss, m);
    if ((tid & 63) == 0) red[tid >> 6] = ss;
    __syncthreads();
    float tot = red[0] + red[1] + red[2] + red[3];
    float scale = 1.0f / fmaxf(sqrtf(tot), 1e-12f);
#pragma unroll
    for (int i = 0; i < 32; ++i)
        out[(size_t)b*8192 + i*256 + tid] = v[i] * scale;
}

extern "C" void kernel_launch(void* const* d_in, const int* in_sizes, int n_in,
                              void* d_out, int out_size, void* d_ws, size_t ws_size,
                              hipStream_t stream)
{
    (void)in_sizes; (void)n_in; (void)out_size; (void)ws_size;
    const float* x = (const float*)d_in[0];
    const float* c = (const float*)d_in[1];
    float* out  = (float*)d_out;
    float* vlad = (float*)d_ws;                       // [32][64][128]
    float* cs   = vlad + (size_t)NB*KC*DD;            // [32][64]
    int*   cnt  = (int*)(cs + (size_t)NB*KC);         // [32]

    hipMemsetAsync(d_ws, 0, (size_t)(NB*KC*DD + NB*KC + NB) * sizeof(float), stream);
    vlad_fused<<<dim3(NP/(TPB*TN), NB), 256, 0, stream>>>(x, c, vlad, cs, cnt, out);
}

// Round 4
// 154.919 us; speedup vs baseline: 1.7951x; 1.7951x over previous
//
#include <hip/hip_runtime.h>

typedef _Float16 half8 __attribute__((ext_vector_type(8)));
typedef _Float16 half4_t __attribute__((ext_vector_type(4)));
typedef float floatx4 __attribute__((ext_vector_type(4)));

static constexpr int NB  = 32;    // batches
static constexpr int NP  = 4096;  // points per batch
static constexpr int DD  = 128;   // dim
static constexpr int KC  = 64;    // clusters
static constexpr int TN  = 64;    // points per tile
static constexpr int TPB = 2;     // tiles per block
static constexpr int SLOTS = NP / (TPB * TN);   // 32 partial slots per batch
static constexpr int SCP = 136;   // sclo pitch (halfwords)
static constexpr int STP = 72;    // sxt / sat pitch (halfwords)

#define ALPHA_  100.0f
#define LOG2E_  1.44269504088896f

// Kernel 1: distances -> softmax -> block-private vlad partial (plain stores,
// no atomics, no fences, no zero-init needed).
__global__ __launch_bounds__(256, 3)
void vlad_main(const float* __restrict__ xg, const float* __restrict__ cg,
               float* __restrict__ vp, float* __restrict__ cpart)
{
    __shared__ __align__(16) _Float16 sxt[DD][STP];   // x tile fp16^T [d][n^swz]
    __shared__ __align__(16) _Float16 sat[KC][STP];   // softmax a^T [k][n^swz]
    __shared__ __align__(16) _Float16 sclo[KC][SCP];  // centroid lo residual [k][d]
    __shared__ float sc2[KC];

    const int tid  = threadIdx.x;
    const int lane = tid & 63;
    const int w    = tid >> 6;
    const int l15  = lane & 15;
    const int quad = lane >> 4;
    const int b    = blockIdx.y;
    const int s    = blockIdx.x;          // slot within batch
    const float* xb = xg + (size_t)b * NP * DD;

    const int nloc = w*16 + l15;
    const int scol = nloc ^ (quad << 4);
    const float* xpt = xb + (size_t)(s*TPB*TN + nloc)*DD + quad*8;

    // ---- issue x tile-0 loads FIRST (hide HBM latency under centroid prep) ----
    float4 fa[4], fb[4];
#pragma unroll
    for (int ks = 0; ks < 4; ++ks) {
        fa[ks] = *(const float4*)(xpt + ks*32);
        fb[ks] = *(const float4*)(xpt + ks*32 + 4);
    }

    // ---- centroid prep: hi-frags in registers, lo tile + c2 in LDS ----
    half8 chi[4][4]; // [mt][ks]: lane holds C[mt*16+l15][ks*32+quad*8 .. +7]
#pragma unroll
    for (int mt = 0; mt < 4; ++mt)
#pragma unroll
        for (int ks = 0; ks < 4; ++ks) {
            const float* p = cg + (mt*16 + l15)*DD + ks*32 + quad*8;
            float4 a  = *(const float4*)p;
            float4 bb = *(const float4*)(p + 4);
            half8 h;
            h[0]=(_Float16)a.x;  h[1]=(_Float16)a.y;  h[2]=(_Float16)a.z;  h[3]=(_Float16)a.w;
            h[4]=(_Float16)bb.x; h[5]=(_Float16)bb.y; h[6]=(_Float16)bb.z; h[7]=(_Float16)bb.w;
            chi[mt][ks] = h;
        }
    {
        int k = tid >> 2, qq = tid & 3;
        const float* rp = cg + k*DD + qq*32;
        float c2p = 0.f;
#pragma unroll
        for (int j = 0; j < 8; ++j) {
            float4 v = *(const float4*)(rp + j*4);
            c2p += v.x*v.x + v.y*v.y + v.z*v.z + v.w*v.w;
            half4_t lo;
            lo[0] = (_Float16)(v.x - (float)(_Float16)v.x);
            lo[1] = (_Float16)(v.y - (float)(_Float16)v.y);
            lo[2] = (_Float16)(v.z - (float)(_Float16)v.z);
            lo[3] = (_Float16)(v.w - (float)(_Float16)v.w);
            *(half4_t*)&sclo[k][(qq*8 + j)*4] = lo;
        }
        c2p += __shfl_xor(c2p, 1);
        c2p += __shfl_xor(c2p, 2);
        if (qq == 0) sc2[k] = c2p;
    }
    __syncthreads();   // sclo / sc2 ready

    floatx4 acc2[8];   // vlad partial: row k = w*16+quad*4+r, col d = nt*16+l15
#pragma unroll
    for (int i = 0; i < 8; ++i) acc2[i] = (floatx4){0.f, 0.f, 0.f, 0.f};
    floatx4 accs = (floatx4){0.f, 0.f, 0.f, 0.f};  // colsum via ones-column MFMA

    half8 onesf;       // B[point][col] = (col==0)
#pragma unroll
    for (int j = 0; j < 8; ++j) onesf[j] = (_Float16)((l15 == 0) ? 1.0f : 0.0f);

#pragma unroll
    for (int tt = 0; tt < TPB; ++tt) {
        // ---- convert staged fp32 -> fp16 frags; ssq ----
        half8 xf[4];
        float ssq = 0.f;
#pragma unroll
        for (int ks = 0; ks < 4; ++ks) {
            half8 h;
            h[0]=(_Float16)fa[ks].x; h[1]=(_Float16)fa[ks].y;
            h[2]=(_Float16)fa[ks].z; h[3]=(_Float16)fa[ks].w;
            h[4]=(_Float16)fb[ks].x; h[5]=(_Float16)fb[ks].y;
            h[6]=(_Float16)fb[ks].z; h[7]=(_Float16)fb[ks].w;
            xf[ks] = h;
            ssq += fa[ks].x*fa[ks].x + fa[ks].y*fa[ks].y + fa[ks].z*fa[ks].z + fa[ks].w*fa[ks].w
                 + fb[ks].x*fb[ks].x + fb[ks].y*fb[ks].y + fb[ks].z*fb[ks].z + fb[ks].w*fb[ks].w;
        }

        // ---- prefetch next tile: latency overlaps GEMM1+softmax+GEMM2 ----
        if (tt + 1 < TPB) {
            const float* xr = xpt + (size_t)(tt + 1) * TN * DD;
#pragma unroll
            for (int ks = 0; ks < 4; ++ks) {
                fa[ks] = *(const float4*)(xr + ks*32);
                fb[ks] = *(const float4*)(xr + ks*32 + 4);
            }
        }

        // ---- write x^T (swizzled; 2-way-max = free) ----
#pragma unroll
        for (int ks = 0; ks < 4; ++ks)
#pragma unroll
            for (int j = 0; j < 8; ++j)
                sxt[ks*32 + quad*8 + j][scol] = xf[ks][j];

        // ---- GEMM1: S^T[cluster][point], c = hi + lo ----
        floatx4 acc1[4];
#pragma unroll
        for (int mt = 0; mt < 4; ++mt) acc1[mt] = (floatx4){0.f, 0.f, 0.f, 0.f};
#pragma unroll
        for (int ks = 0; ks < 4; ++ks) {
#pragma unroll
            for (int mt = 0; mt < 4; ++mt) {
                half8 cl = *(const half8*)&sclo[mt*16 + l15][ks*32 + quad*8];
                acc1[mt] = __builtin_amdgcn_mfma_f32_16x16x32_f16(chi[mt][ks], xf[ks], acc1[mt], 0, 0, 0);
                acc1[mt] = __builtin_amdgcn_mfma_f32_16x16x32_f16(cl,          xf[ks], acc1[mt], 0, 0, 0);
            }
        }
        ssq += __shfl_xor(ssq, 16);
        ssq += __shfl_xor(ssq, 32);

        // ---- softmax over 64 clusters for this lane's point ----
        float dist[4][4];
#pragma unroll
        for (int mt = 0; mt < 4; ++mt) {
            floatx4 c2v = *(const floatx4*)&sc2[mt*16 + quad*4];
#pragma unroll
            for (int r = 0; r < 4; ++r) {
                float d2 = ssq + c2v[r] - 2.f*acc1[mt][r];
                dist[mt][r] = sqrtf(fmaxf(d2, 0.f));
            }
        }
        float dmin = dist[0][0];
#pragma unroll
        for (int mt = 0; mt < 4; ++mt)
#pragma unroll
            for (int r = 0; r < 4; ++r) dmin = fminf(dmin, dist[mt][r]);
        dmin = fminf(dmin, __shfl_xor(dmin, 16));
        dmin = fminf(dmin, __shfl_xor(dmin, 32));
        float pv[4][4];
        float psum = 0.f;
#pragma unroll
        for (int mt = 0; mt < 4; ++mt)
#pragma unroll
            for (int r = 0; r < 4; ++r) {
                float e = exp2f((dmin - dist[mt][r]) * (ALPHA_ * LOG2E_));
                pv[mt][r] = e; psum += e;
            }
        psum += __shfl_xor(psum, 16);
        psum += __shfl_xor(psum, 32);
        float invs = 1.0f / psum;
#pragma unroll
        for (int mt = 0; mt < 4; ++mt)
#pragma unroll
            for (int r = 0; r < 4; ++r)
                sat[mt*16 + quad*4 + r][scol] = (_Float16)(pv[mt][r] * invs);
        __syncthreads();   // sxt + sat visible

        // ---- GEMM2: vlad[k][d] += a^T · x ; colsum via ones column ----
#pragma unroll
        for (int ks2 = 0; ks2 < 2; ++ks2) {
            const int nbase = ks2*32 + quad*8;
            half8 af = *(const half8*)&sat[w*16 + l15][nbase ^ ((l15 >> 2) << 4)];
            accs = __builtin_amdgcn_mfma_f32_16x16x32_f16(af, onesf, accs, 0, 0, 0);
#pragma unroll
            for (int nt = 0; nt < 8; ++nt) {
                const int d = nt*16 + l15;
                half8 bf = *(const half8*)&sxt[d][nbase ^ (((d >> 3) & 3) << 4)];
                acc2[nt] = __builtin_amdgcn_mfma_f32_16x16x32_f16(af, bf, acc2[nt], 0, 0, 0);
            }
        }
        __syncthreads();   // reads done before next tile overwrites
    }

    // ---- epilogue: plain coalesced stores into this block's private slot ----
    float* slot = vp + ((size_t)b*SLOTS + s) * (KC*DD);
#pragma unroll
    for (int nt = 0; nt < 8; ++nt)
#pragma unroll
        for (int r = 0; r < 4; ++r) {
            int k = w*16 + quad*4 + r;
            int d = nt*16 + l15;
            slot[k*DD + d] = acc2[nt][r];
        }
    if (l15 == 0) {
#pragma unroll
        for (int r = 0; r < 4; ++r)
            cpart[((size_t)b*SLOTS + s)*KC + w*16 + quad*4 + r] = accs[r];
    }
}

// Kernel 2: wide reduction of partials (8 blocks per batch for HBM BW),
// subtract colsum*c, write reduced vlad + per-chunk sum-of-squares.
__global__ __launch_bounds__(256)
void vlad_reduce(const float* __restrict__ vp, const float* __restrict__ cpart,
                 const float* __restrict__ cg, float* __restrict__ vfull,
                 float* __restrict__ ssp)
{
    __shared__ float scs[KC];
    __shared__ float red[4];
    const int b   = blockIdx.x >> 3;
    const int q   = blockIdx.x & 7;       // 1024-element chunk
    const int tid = threadIdx.x;

    if (tid < KC) {
        float cs = 0.f;
        for (int si = 0; si < SLOTS; ++si)
            cs += cpart[((size_t)b*SLOTS + si)*KC + tid];
        scs[tid] = cs;
    }
    __syncthreads();

    const float* vpb = vp + (size_t)b*SLOTS*(KC*DD);
    float ss = 0.f;
#pragma unroll
    for (int i = 0; i < 4; ++i) {
        int idx = q*1024 + i*256 + tid;
        float a = 0.f;
#pragma unroll
        for (int si = 0; si < SLOTS; ++si)
            a += vpb[(size_t)si*(KC*DD) + idx];
        a -= scs[idx >> 7] * cg[idx];
        vfull[(size_t)b*(KC*DD) + idx] = a;
        ss += a * a;
    }
#pragma unroll
    for (int m = 1; m < 64; m <<= 1) ss += __shfl_xor(ss, m);
    if ((tid & 63) == 0) red[tid >> 6] = ss;
    __syncthreads();
    if (tid == 0) ssp[b*8 + q] = red[0] + red[1] + red[2] + red[3];
}

// Kernel 3: L2-normalize per batch
__global__ __launch_bounds__(256)
void vlad_norm(const float* __restrict__ vfull, const float* __restrict__ ssp,
               float* __restrict__ out)
{
    const int b   = blockIdx.x;
    const int tid = threadIdx.x;
    float tot = 0.f;
#pragma unroll
    for (int q = 0; q < 8; ++q) tot += ssp[b*8 + q];
    float scale = 1.0f / fmaxf(sqrtf(tot), 1e-12f);
#pragma unroll
    for (int i = 0; i < 32; ++i) {
        int idx = i*256 + tid;
        out[(size_t)b*(KC*DD) + idx] = vfull[(size_t)b*(KC*DD) + idx] * scale;
    }
}

extern "C" void kernel_launch(void* const* d_in, const int* in_sizes, int n_in,
                              void* d_out, int out_size, void* d_ws, size_t ws_size,
                              hipStream_t stream)
{
    (void)in_sizes; (void)n_in; (void)out_size; (void)ws_size;
    const float* x = (const float*)d_in[0];
    const float* c = (const float*)d_in[1];
    float* out   = (float*)d_out;
    float* vp    = (float*)d_ws;                             // [32][32][64][128] = 32 MB
    float* cpart = vp + (size_t)NB*SLOTS*KC*DD;              // [32][32][64]
    float* vfull = cpart + (size_t)NB*SLOTS*KC;              // [32][8192]
    float* ssp   = vfull + (size_t)NB*KC*DD;                 // [32][8]

    vlad_main<<<dim3(SLOTS, NB), 256, 0, stream>>>(x, c, vp, cpart);
    vlad_reduce<<<NB*8, 256, 0, stream>>>(vp, cpart, c, vfull, ssp);
    vlad_norm<<<NB, 256, 0, stream>>>(vfull, ssp, out);
}

// Round 5
// 117.127 us; speedup vs baseline: 2.3744x; 1.3227x over previous
//
#include <hip/hip_runtime.h>

typedef _Float16 half8 __attribute__((ext_vector_type(8)));
typedef _Float16 half4_t __attribute__((ext_vector_type(4)));
typedef float floatx4 __attribute__((ext_vector_type(4)));

static constexpr int NB  = 32;    // batches
static constexpr int NP  = 4096;  // points per batch
static constexpr int DD  = 128;   // dim
static constexpr int KC  = 64;    // clusters
static constexpr int TN  = 64;    // points per tile
static constexpr int TPB = 4;     // tiles per block
static constexpr int SLOTS = NP / (TPB * TN);   // 16 partial slots per batch
static constexpr int SCP = 136;   // sclo pitch (halfwords)
static constexpr int STP = 72;    // sxt / sat pitch (halfwords)

#define ALPHA_  100.0f
#define LOG2E_  1.44269504088896f

// Workgroup barrier that waits ONLY on LDS (lgkmcnt), leaving prefetched
// global loads in flight. __syncthreads() would emit s_waitcnt vmcnt(0)
// and drain the prefetch on the critical path (m97-plateau mechanism).
#define LGKM_BARRIER() asm volatile("s_waitcnt lgkmcnt(0)\ns_barrier" ::: "memory")

// Kernel 1: distances -> softmax -> block-private vlad partial (plain stores).
__global__ __launch_bounds__(256, 2)
void vlad_main(const float* __restrict__ xg, const float* __restrict__ cg,
               float* __restrict__ vp, float* __restrict__ cpart)
{
    __shared__ __align__(16) _Float16 sxt[2][DD][STP];  // x^T [d][n^swz], dbuf
    __shared__ __align__(16) _Float16 sat[2][KC][STP];  // a^T [k][n^swz], dbuf
    __shared__ __align__(16) _Float16 sclo[KC][SCP];    // centroid lo residual
    __shared__ float sc2[KC];

    const int tid  = threadIdx.x;
    const int lane = tid & 63;
    const int w    = tid >> 6;
    const int l15  = lane & 15;
    const int quad = lane >> 4;
    const int b    = blockIdx.y;
    const int s    = blockIdx.x;          // slot within batch
    const float* xb = xg + (size_t)b * NP * DD;

    const int nloc = w*16 + l15;
    const int scol = nloc ^ (quad << 4);
    const float* xpt = xb + (size_t)(s*TPB*TN + nloc)*DD + quad*8;

    // ---- issue x tile-0 loads FIRST (cold HBM; hide under centroid prep) ----
    float4 fa[4], fb[4];
#pragma unroll
    for (int ks = 0; ks < 4; ++ks) {
        fa[ks] = *(const float4*)(xpt + ks*32);
        fb[ks] = *(const float4*)(xpt + ks*32 + 4);
    }

    // ---- centroid prep: hi-frags in registers, lo tile + c2 in LDS ----
    half8 chi[4][4]; // [mt][ks]: lane holds C[mt*16+l15][ks*32+quad*8 .. +7]
#pragma unroll
    for (int mt = 0; mt < 4; ++mt)
#pragma unroll
        for (int ks = 0; ks < 4; ++ks) {
            const float* p = cg + (mt*16 + l15)*DD + ks*32 + quad*8;
            float4 a  = *(const float4*)p;
            float4 bb = *(const float4*)(p + 4);
            half8 h;
            h[0]=(_Float16)a.x;  h[1]=(_Float16)a.y;  h[2]=(_Float16)a.z;  h[3]=(_Float16)a.w;
            h[4]=(_Float16)bb.x; h[5]=(_Float16)bb.y; h[6]=(_Float16)bb.z; h[7]=(_Float16)bb.w;
            chi[mt][ks] = h;
        }
    {
        int k = tid >> 2, qq = tid & 3;
        const float* rp = cg + k*DD + qq*32;
        float c2p = 0.f;
#pragma unroll
        for (int j = 0; j < 8; ++j) {
            float4 v = *(const float4*)(rp + j*4);
            c2p += v.x*v.x + v.y*v.y + v.z*v.z + v.w*v.w;
            half4_t lo;
            lo[0] = (_Float16)(v.x - (float)(_Float16)v.x);
            lo[1] = (_Float16)(v.y - (float)(_Float16)v.y);
            lo[2] = (_Float16)(v.z - (float)(_Float16)v.z);
            lo[3] = (_Float16)(v.w - (float)(_Float16)v.w);
            *(half4_t*)&sclo[k][(qq*8 + j)*4] = lo;
        }
        c2p += __shfl_xor(c2p, 1);
        c2p += __shfl_xor(c2p, 2);
        if (qq == 0) sc2[k] = c2p;
    }
    LGKM_BARRIER();   // sclo / sc2 ready (x tile-0 loads stay in flight)

    floatx4 acc2[8];   // vlad partial: row k = w*16+quad*4+r, col d = nt*16+l15
#pragma unroll
    for (int i = 0; i < 8; ++i) acc2[i] = (floatx4){0.f, 0.f, 0.f, 0.f};
    floatx4 accs = (floatx4){0.f, 0.f, 0.f, 0.f};  // colsum via ones-column MFMA

    half8 onesf;       // B[point][col] = (col==0)
#pragma unroll
    for (int j = 0; j < 8; ++j) onesf[j] = (_Float16)((l15 == 0) ? 1.0f : 0.0f);

#pragma unroll
    for (int tt = 0; tt < TPB; ++tt) {
        const int pb = tt & 1;   // LDS buffer parity

        // ---- convert staged fp32 -> fp16 frags; per-lane ssq ----
        half8 xf[4];
        float ssq = 0.f;
#pragma unroll
        for (int ks = 0; ks < 4; ++ks) {
            half8 h;
            h[0]=(_Float16)fa[ks].x; h[1]=(_Float16)fa[ks].y;
            h[2]=(_Float16)fa[ks].z; h[3]=(_Float16)fa[ks].w;
            h[4]=(_Float16)fb[ks].x; h[5]=(_Float16)fb[ks].y;
            h[6]=(_Float16)fb[ks].z; h[7]=(_Float16)fb[ks].w;
            xf[ks] = h;
            ssq += fa[ks].x*fa[ks].x + fa[ks].y*fa[ks].y + fa[ks].z*fa[ks].z + fa[ks].w*fa[ks].w
                 + fb[ks].x*fb[ks].x + fb[ks].y*fb[ks].y + fb[ks].z*fb[ks].z + fb[ks].w*fb[ks].w;
        }

        // ---- prefetch next tile; stays in flight across the lgkm barrier ----
        if (tt + 1 < TPB) {
            const float* xr = xpt + (size_t)(tt + 1) * TN * DD;
#pragma unroll
            for (int ks = 0; ks < 4; ++ks) {
                fa[ks] = *(const float4*)(xr + ks*32);
                fb[ks] = *(const float4*)(xr + ks*32 + 4);
            }
        }

        // ---- write x^T (swizzled; 2-way max = free) ----
#pragma unroll
        for (int ks = 0; ks < 4; ++ks)
#pragma unroll
            for (int j = 0; j < 8; ++j)
                sxt[pb][ks*32 + quad*8 + j][scol] = xf[ks][j];

        // ---- GEMM1: S^T[cluster][point], c = hi + lo ----
        floatx4 acc1[4];
#pragma unroll
        for (int mt = 0; mt < 4; ++mt) acc1[mt] = (floatx4){0.f, 0.f, 0.f, 0.f};
#pragma unroll
        for (int ks = 0; ks < 4; ++ks) {
#pragma unroll
            for (int mt = 0; mt < 4; ++mt) {
                half8 cl = *(const half8*)&sclo[mt*16 + l15][ks*32 + quad*8];
                acc1[mt] = __builtin_amdgcn_mfma_f32_16x16x32_f16(chi[mt][ks], xf[ks], acc1[mt], 0, 0, 0);
                acc1[mt] = __builtin_amdgcn_mfma_f32_16x16x32_f16(cl,          xf[ks], acc1[mt], 0, 0, 0);
            }
        }
        ssq += __shfl_xor(ssq, 16);
        ssq += __shfl_xor(ssq, 32);

        // ---- softmax over 64 clusters for this lane's point ----
        float dist[4][4];
#pragma unroll
        for (int mt = 0; mt < 4; ++mt) {
            floatx4 c2v = *(const floatx4*)&sc2[mt*16 + quad*4];
#pragma unroll
            for (int r = 0; r < 4; ++r) {
                float d2 = ssq + c2v[r] - 2.f*acc1[mt][r];
                dist[mt][r] = sqrtf(fmaxf(d2, 0.f));
            }
        }
        float dmin = dist[0][0];
#pragma unroll
        for (int mt = 0; mt < 4; ++mt)
#pragma unroll
            for (int r = 0; r < 4; ++r) dmin = fminf(dmin, dist[mt][r]);
        dmin = fminf(dmin, __shfl_xor(dmin, 16));
        dmin = fminf(dmin, __shfl_xor(dmin, 32));
        float pv[4][4];
        float psum = 0.f;
#pragma unroll
        for (int mt = 0; mt < 4; ++mt)
#pragma unroll
            for (int r = 0; r < 4; ++r) {
                float e = exp2f((dmin - dist[mt][r]) * (ALPHA_ * LOG2E_));
                pv[mt][r] = e; psum += e;
            }
        psum += __shfl_xor(psum, 16);
        psum += __shfl_xor(psum, 32);
        float invs = 1.0f / psum;
#pragma unroll
        for (int mt = 0; mt < 4; ++mt)
#pragma unroll
            for (int r = 0; r < 4; ++r)
                sat[pb][mt*16 + quad*4 + r][scol] = (_Float16)(pv[mt][r] * invs);

        LGKM_BARRIER();   // sxt/sat[pb] visible; prefetch loads NOT drained

        // ---- GEMM2: vlad[k][d] += a^T · x ; colsum via ones column ----
        // Double buffer makes this safe with no trailing barrier: nobody can
        // rewrite buf[pb] until all waves pass the NEXT tile's barrier, which
        // postdates every read below.
#pragma unroll
        for (int ks2 = 0; ks2 < 2; ++ks2) {
            const int nbase = ks2*32 + quad*8;
            half8 af = *(const half8*)&sat[pb][w*16 + l15][nbase ^ ((l15 >> 2) << 4)];
            accs = __builtin_amdgcn_mfma_f32_16x16x32_f16(af, onesf, accs, 0, 0, 0);
#pragma unroll
            for (int nt = 0; nt < 8; ++nt) {
                const int d = nt*16 + l15;
                half8 bf = *(const half8*)&sxt[pb][d][nbase ^ (((d >> 3) & 3) << 4)];
                acc2[nt] = __builtin_amdgcn_mfma_f32_16x16x32_f16(af, bf, acc2[nt], 0, 0, 0);
            }
        }
    }

    // ---- epilogue: plain coalesced stores into this block's private slot ----
    float* slot = vp + ((size_t)b*SLOTS + s) * (KC*DD);
#pragma unroll
    for (int nt = 0; nt < 8; ++nt)
#pragma unroll
        for (int r = 0; r < 4; ++r) {
            int k = w*16 + quad*4 + r;
            int d = nt*16 + l15;
            slot[k*DD + d] = acc2[nt][r];
        }
    if (l15 == 0) {
#pragma unroll
        for (int r = 0; r < 4; ++r)
            cpart[((size_t)b*SLOTS + s)*KC + w*16 + quad*4 + r] = accs[r];
    }
}

// Kernel 2: reduce partials (8 blocks/batch), subtract colsum*c, write reduced
// vlad + per-chunk sum-of-squares. float4 throughout.
__global__ __launch_bounds__(256)
void vlad_reduce(const float* __restrict__ vp, const float* __restrict__ cpart,
                 const float* __restrict__ cg, float* __restrict__ vfull,
                 float* __restrict__ ssp)
{
    __shared__ float scs[KC];
    __shared__ float red[4];
    const int b   = blockIdx.x >> 3;
    const int q   = blockIdx.x & 7;       // 1024-element chunk
    const int tid = threadIdx.x;

    if (tid < KC) {
        float cs = 0.f;
#pragma unroll
        for (int si = 0; si < SLOTS; ++si)
            cs += cpart[((size_t)b*SLOTS + si)*KC + tid];
        scs[tid] = cs;
    }
    __syncthreads();

    const int idx = q*1024 + tid*4;       // 4 consecutive elements per thread
    const float* vpb = vp + (size_t)b*SLOTS*(KC*DD) + idx;
    float4 a = {0.f, 0.f, 0.f, 0.f};
#pragma unroll
    for (int si = 0; si < SLOTS; ++si) {
        float4 t = *(const float4*)(vpb + (size_t)si*(KC*DD));
        a.x += t.x; a.y += t.y; a.z += t.z; a.w += t.w;
    }
    float cs = scs[idx >> 7];             // same cluster for all 4 (128 | idx)
    float4 cv = *(const float4*)(cg + idx);
    a.x -= cs*cv.x; a.y -= cs*cv.y; a.z -= cs*cv.z; a.w -= cs*cv.w;
    *(float4*)(vfull + (size_t)b*(KC*DD) + idx) = a;
    float ss = a.x*a.x + a.y*a.y + a.z*a.z + a.w*a.w;
#pragma unroll
    for (int m = 1; m < 64; m <<= 1) ss += __shfl_xor(ss, m);
    if ((tid & 63) == 0) red[tid >> 6] = ss;
    __syncthreads();
    if (tid == 0) ssp[b*8 + q] = red[0] + red[1] + red[2] + red[3];
}

// Kernel 3: L2-normalize per batch
__global__ __launch_bounds__(256)
void vlad_norm(const float* __restrict__ vfull, const float* __restrict__ ssp,
               float* __restrict__ out)
{
    const int b   = blockIdx.x;
    const int tid = threadIdx.x;
    float tot = 0.f;
#pragma unroll
    for (int q = 0; q < 8; ++q) tot += ssp[b*8 + q];
    float scale = 1.0f / fmaxf(sqrtf(tot), 1e-12f);
#pragma unroll
    for (int i = 0; i < 8; ++i) {
        int idx = i*1024 + tid*4;
        float4 v = *(const float4*)(vfull + (size_t)b*(KC*DD) + idx);
        v.x *= scale; v.y *= scale; v.z *= scale; v.w *= scale;
        *(float4*)(out + (size_t)b*(KC*DD) + idx) = v;
    }
}

extern "C" void kernel_launch(void* const* d_in, const int* in_sizes, int n_in,
                              void* d_out, int out_size, void* d_ws, size_t ws_size,
                              hipStream_t stream)
{
    (void)in_sizes; (void)n_in; (void)out_size; (void)ws_size;
    const float* x = (const float*)d_in[0];
    const float* c = (const float*)d_in[1];
    float* out   = (float*)d_out;
    float* vp    = (float*)d_ws;                             // [32][16][64][128] = 16.8 MB
    float* cpart = vp + (size_t)NB*SLOTS*KC*DD;              // [32][16][64]
    float* vfull = cpart + (size_t)NB*SLOTS*KC;              // [32][8192]
    float* ssp   = vfull + (size_t)NB*KC*DD;                 // [32][8]

    vlad_main<<<dim3(SLOTS, NB), 256, 0, stream>>>(x, c, vp, cpart);
    vlad_reduce<<<NB*8, 256, 0, stream>>>(vp, cpart, c, vfull, ssp);
    vlad_norm<<<NB, 256, 0, stream>>>(vfull, ssp, out);
}

// Round 6
// 113.198 us; speedup vs baseline: 2.4568x; 1.0347x over previous
//
#include <hip/hip_runtime.h>

typedef _Float16 half8 __attribute__((ext_vector_type(8)));
typedef float floatx4 __attribute__((ext_vector_type(4)));

static constexpr int NB  = 32;    // batches
static constexpr int NP  = 4096;  // points per batch
static constexpr int DD  = 128;   // dim
static constexpr int KC  = 64;    // clusters
static constexpr int TN  = 64;    // points per tile
static constexpr int TPB = 4;     // tiles per block
static constexpr int SLOTS = NP / (TPB * TN);   // 16 partial slots per batch
static constexpr int STP = 72;    // sxt / sat pitch (halfwords).  NOTE: stride
                                  // 36 dwords ≡ 4 (mod 32 banks) is what makes
                                  // the XOR-swizzled b128 reads 2-way-max; do
                                  // not "optimize" to 64.

#define ALPHA_  100.0f
#define LOG2E_  1.44269504088896f

// Workgroup barrier that waits ONLY on LDS (lgkmcnt), leaving prefetched
// global loads in flight. __syncthreads() would emit s_waitcnt vmcnt(0)
// and drain the prefetch on the critical path.
#define LGKM_BARRIER() asm volatile("s_waitcnt lgkmcnt(0)\ns_barrier" ::: "memory")

// Kernel 1: distances -> softmax -> block-private vlad partial (plain stores).
// Precision note: x and c both pure fp16 (single MFMA pass). Harness compares
// in bf16; measured error floor is 1 bf16 ulp (4.88e-4), c-rounding adds ~sqrt2.
__global__ __launch_bounds__(256, 2)
void vlad_main(const float* __restrict__ xg, const float* __restrict__ cg,
               float* __restrict__ vp, float* __restrict__ cpart)
{
    __shared__ __align__(16) _Float16 sxt[2][DD][STP];  // x^T [d][n^swz], dbuf
    __shared__ __align__(16) _Float16 sat[2][KC][STP];  // a^T [k][n^swz], dbuf
    __shared__ float sc2[KC];

    const int tid  = threadIdx.x;
    const int lane = tid & 63;
    const int w    = tid >> 6;
    const int l15  = lane & 15;
    const int quad = lane >> 4;
    const int b    = blockIdx.y;
    const int s    = blockIdx.x;          // slot within batch
    const float* xb = xg + (size_t)b * NP * DD;

    const int nloc = w*16 + l15;
    const int scol = nloc ^ (quad << 4);
    const float* xpt = xb + (size_t)(s*TPB*TN + nloc)*DD + quad*8;

    // ---- issue x tile-0 loads FIRST (cold HBM; hide under centroid prep) ----
    float4 fa[4], fb[4];
#pragma unroll
    for (int ks = 0; ks < 4; ++ks) {
        fa[ks] = *(const float4*)(xpt + ks*32);
        fb[ks] = *(const float4*)(xpt + ks*32 + 4);
    }

    // ---- centroid prep: fp16 hi-frags in registers; c2 (fp32, exact) via
    //      cross-quad shuffles of the same loads ----
    half8 chi[4][4]; // [mt][ks]: lane holds C[mt*16+l15][ks*32+quad*8 .. +7]
    float c2p[4];
#pragma unroll
    for (int mt = 0; mt < 4; ++mt) {
        c2p[mt] = 0.f;
#pragma unroll
        for (int ks = 0; ks < 4; ++ks) {
            const float* p = cg + (mt*16 + l15)*DD + ks*32 + quad*8;
            float4 a  = *(const float4*)p;
            float4 bb = *(const float4*)(p + 4);
            half8 h;
            h[0]=(_Float16)a.x;  h[1]=(_Float16)a.y;  h[2]=(_Float16)a.z;  h[3]=(_Float16)a.w;
            h[4]=(_Float16)bb.x; h[5]=(_Float16)bb.y; h[6]=(_Float16)bb.z; h[7]=(_Float16)bb.w;
            chi[mt][ks] = h;
            c2p[mt] += a.x*a.x + a.y*a.y + a.z*a.z + a.w*a.w
                     + bb.x*bb.x + bb.y*bb.y + bb.z*bb.z + bb.w*bb.w;
        }
    }
#pragma unroll
    for (int mt = 0; mt < 4; ++mt) {
        // quads hold disjoint column segments of the SAME row mt*16+l15
        float s2 = c2p[mt];
        s2 += __shfl_xor(s2, 16);
        s2 += __shfl_xor(s2, 32);
        if (quad == 0 && w == 0) sc2[mt*16 + l15] = s2;
    }
    LGKM_BARRIER();   // sc2 ready (x tile-0 loads stay in flight)

    floatx4 acc2[8];   // vlad partial: row k = w*16+quad*4+r, col d = nt*16+l15
#pragma unroll
    for (int i = 0; i < 8; ++i) acc2[i] = (floatx4){0.f, 0.f, 0.f, 0.f};
    floatx4 accs = (floatx4){0.f, 0.f, 0.f, 0.f};  // colsum via ones-column MFMA

    half8 onesf;       // B[point][col] = (col==0)
#pragma unroll
    for (int j = 0; j < 8; ++j) onesf[j] = (_Float16)((l15 == 0) ? 1.0f : 0.0f);

#pragma unroll
    for (int tt = 0; tt < TPB; ++tt) {
        const int pb = tt & 1;   // LDS buffer parity

        // ---- convert staged fp32 -> fp16 frags; per-lane ssq ----
        half8 xf[4];
        float ssq = 0.f;
#pragma unroll
        for (int ks = 0; ks < 4; ++ks) {
            half8 h;
            h[0]=(_Float16)fa[ks].x; h[1]=(_Float16)fa[ks].y;
            h[2]=(_Float16)fa[ks].z; h[3]=(_Float16)fa[ks].w;
            h[4]=(_Float16)fb[ks].x; h[5]=(_Float16)fb[ks].y;
            h[6]=(_Float16)fb[ks].z; h[7]=(_Float16)fb[ks].w;
            xf[ks] = h;
            ssq += fa[ks].x*fa[ks].x + fa[ks].y*fa[ks].y + fa[ks].z*fa[ks].z + fa[ks].w*fa[ks].w
                 + fb[ks].x*fb[ks].x + fb[ks].y*fb[ks].y + fb[ks].z*fb[ks].z + fb[ks].w*fb[ks].w;
        }

        // ---- prefetch next tile; stays in flight across the lgkm barrier ----
        if (tt + 1 < TPB) {
            const float* xr = xpt + (size_t)(tt + 1) * TN * DD;
#pragma unroll
            for (int ks = 0; ks < 4; ++ks) {
                fa[ks] = *(const float4*)(xr + ks*32);
                fb[ks] = *(const float4*)(xr + ks*32 + 4);
            }
        }

        // ---- write x^T (swizzled; 2-way max = free) ----
#pragma unroll
        for (int ks = 0; ks < 4; ++ks)
#pragma unroll
            for (int j = 0; j < 8; ++j)
                sxt[pb][ks*32 + quad*8 + j][scol] = xf[ks][j];

        // ---- GEMM1: S^T[cluster][point], c fp16 ----
        floatx4 acc1[4];
#pragma unroll
        for (int mt = 0; mt < 4; ++mt) acc1[mt] = (floatx4){0.f, 0.f, 0.f, 0.f};
#pragma unroll
        for (int ks = 0; ks < 4; ++ks)
#pragma unroll
            for (int mt = 0; mt < 4; ++mt)
                acc1[mt] = __builtin_amdgcn_mfma_f32_16x16x32_f16(chi[mt][ks], xf[ks], acc1[mt], 0, 0, 0);
        ssq += __shfl_xor(ssq, 16);
        ssq += __shfl_xor(ssq, 32);

        // ---- softmax over 64 clusters for this lane's point ----
        float dist[4][4];
#pragma unroll
        for (int mt = 0; mt < 4; ++mt) {
            floatx4 c2v = *(const floatx4*)&sc2[mt*16 + quad*4];
#pragma unroll
            for (int r = 0; r < 4; ++r) {
                float d2 = ssq + c2v[r] - 2.f*acc1[mt][r];
                dist[mt][r] = sqrtf(fmaxf(d2, 0.f));
            }
        }
        float dmin = dist[0][0];
#pragma unroll
        for (int mt = 0; mt < 4; ++mt)
#pragma unroll
            for (int r = 0; r < 4; ++r) dmin = fminf(dmin, dist[mt][r]);
        dmin = fminf(dmin, __shfl_xor(dmin, 16));
        dmin = fminf(dmin, __shfl_xor(dmin, 32));
        float pv[4][4];
        float psum = 0.f;
#pragma unroll
        for (int mt = 0; mt < 4; ++mt)
#pragma unroll
            for (int r = 0; r < 4; ++r) {
                float e = exp2f((dmin - dist[mt][r]) * (ALPHA_ * LOG2E_));
                pv[mt][r] = e; psum += e;
            }
        psum += __shfl_xor(psum, 16);
        psum += __shfl_xor(psum, 32);
        float invs = 1.0f / psum;
#pragma unroll
        for (int mt = 0; mt < 4; ++mt)
#pragma unroll
            for (int r = 0; r < 4; ++r)
                sat[pb][mt*16 + quad*4 + r][scol] = (_Float16)(pv[mt][r] * invs);

        LGKM_BARRIER();   // sxt/sat[pb] visible; prefetch loads NOT drained

        // ---- GEMM2: vlad[k][d] += a^T · x ; colsum via ones column ----
        // Double buffer: buf[pb] can't be rewritten until all waves pass the
        // NEXT tile's barrier, which postdates every read below.
#pragma unroll
        for (int ks2 = 0; ks2 < 2; ++ks2) {
            const int nbase = ks2*32 + quad*8;
            half8 af = *(const half8*)&sat[pb][w*16 + l15][nbase ^ ((l15 >> 2) << 4)];
            accs = __builtin_amdgcn_mfma_f32_16x16x32_f16(af, onesf, accs, 0, 0, 0);
#pragma unroll
            for (int nt = 0; nt < 8; ++nt) {
                const int d = nt*16 + l15;
                half8 bf = *(const half8*)&sxt[pb][d][nbase ^ (((d >> 3) & 3) << 4)];
                acc2[nt] = __builtin_amdgcn_mfma_f32_16x16x32_f16(af, bf, acc2[nt], 0, 0, 0);
            }
        }
    }

    // ---- epilogue: plain coalesced stores into this block's private slot ----
    float* slot = vp + ((size_t)b*SLOTS + s) * (KC*DD);
#pragma unroll
    for (int nt = 0; nt < 8; ++nt)
#pragma unroll
        for (int r = 0; r < 4; ++r) {
            int k = w*16 + quad*4 + r;
            int d = nt*16 + l15;
            slot[k*DD + d] = acc2[nt][r];
        }
    if (l15 == 0) {
#pragma unroll
        for (int r = 0; r < 4; ++r)
            cpart[((size_t)b*SLOTS + s)*KC + w*16 + quad*4 + r] = accs[r];
    }
}

// Kernel 2: reduce partials (8 blocks/batch), subtract colsum*c, write reduced
// vlad + per-chunk sum-of-squares. float4 throughout.
__global__ __launch_bounds__(256)
void vlad_reduce(const float* __restrict__ vp, const float* __restrict__ cpart,
                 const float* __restrict__ cg, float* __restrict__ vfull,
                 float* __restrict__ ssp)
{
    __shared__ float scs[KC];
    __shared__ float red[4];
    const int b   = blockIdx.x >> 3;
    const int q   = blockIdx.x & 7;       // 1024-element chunk
    const int tid = threadIdx.x;

    if (tid < KC) {
        float cs = 0.f;
#pragma unroll
        for (int si = 0; si < SLOTS; ++si)
            cs += cpart[((size_t)b*SLOTS + si)*KC + tid];
        scs[tid] = cs;
    }
    __syncthreads();

    const int idx = q*1024 + tid*4;       // 4 consecutive elements per thread
    const float* vpb = vp + (size_t)b*SLOTS*(KC*DD) + idx;
    float4 a = {0.f, 0.f, 0.f, 0.f};
#pragma unroll
    for (int si = 0; si < SLOTS; ++si) {
        float4 t = *(const float4*)(vpb + (size_t)si*(KC*DD));
        a.x += t.x; a.y += t.y; a.z += t.z; a.w += t.w;
    }
    float cs = scs[idx >> 7];             // same cluster for all 4 (128 | idx)
    float4 cv = *(const float4*)(cg + idx);
    a.x -= cs*cv.x; a.y -= cs*cv.y; a.z -= cs*cv.z; a.w -= cs*cv.w;
    *(float4*)(vfull + (size_t)b*(KC*DD) + idx) = a;
    float ss = a.x*a.x + a.y*a.y + a.z*a.z + a.w*a.w;
#pragma unroll
    for (int m = 1; m < 64; m <<= 1) ss += __shfl_xor(ss, m);
    if ((tid & 63) == 0) red[tid >> 6] = ss;
    __syncthreads();
    if (tid == 0) ssp[b*8 + q] = red[0] + red[1] + red[2] + red[3];
}

// Kernel 3: L2-normalize per batch
__global__ __launch_bounds__(256)
void vlad_norm(const float* __restrict__ vfull, const float* __restrict__ ssp,
               float* __restrict__ out)
{
    const int b   = blockIdx.x;
    const int tid = threadIdx.x;
    float tot = 0.f;
#pragma unroll
    for (int q = 0; q < 8; ++q) tot += ssp[b*8 + q];
    float scale = 1.0f / fmaxf(sqrtf(tot), 1e-12f);
#pragma unroll
    for (int i = 0; i < 8; ++i) {
        int idx = i*1024 + tid*4;
        float4 v = *(const float4*)(vfull + (size_t)b*(KC*DD) + idx);
        v.x *= scale; v.y *= scale; v.z *= scale; v.w *= scale;
        *(float4*)(out + (size_t)b*(KC*DD) + idx) = v;
    }
}

extern "C" void kernel_launch(void* const* d_in, const int* in_sizes, int n_in,
                              void* d_out, int out_size, void* d_ws, size_t ws_size,
                              hipStream_t stream)
{
    (void)in_sizes; (void)n_in; (void)out_size; (void)ws_size;
    const float* x = (const float*)d_in[0];
    const float* c = (const float*)d_in[1];
    float* out   = (float*)d_out;
    float* vp    = (float*)d_ws;                             // [32][16][64][128] = 16.8 MB
    float* cpart = vp + (size_t)NB*SLOTS*KC*DD;              // [32][16][64]
    float* vfull = cpart + (size_t)NB*SLOTS*KC;              // [32][8192]
    float* ssp   = vfull + (size_t)NB*KC*DD;                 // [32][8]

    vlad_main<<<dim3(SLOTS, NB), 256, 0, stream>>>(x, c, vp, cpart);
    vlad_reduce<<<NB*8, 256, 0, stream>>>(vp, cpart, c, vfull, ssp);
    vlad_norm<<<NB, 256, 0, stream>>>(vfull, ssp, out);
}